// Round 21
// baseline (564.422 us; speedup 1.0000x reference)
//
#include <hip/hip_runtime.h>

// SNN: conv2d(3x3, same, no bias, Cin=Cout=64) + LIF scan (tau=2, v_th=1, hard reset)
// Numerics contract (R13, PASS R14/R15/R20):
//   conv: f32, SINGLE FMA chain per output in flat (ci, ky, kx) order g=ci*9+k
//   scan: float64, v' = v + (z - v)*0.5, spike = v' >= 1.0, hard reset to 0.
// R21: fit the FAST 64-VGPR regime WITHOUT spills by halving per-thread state:
//   512 threads/block, 8 waves x 8 c_out (was 4 waves x 16). Per-thread live:
//   r[13] + v[8]f64(16) + z[8] + nb[9] + addr ~= 60 <= 64. Empirics: VGPR-64
//   builds are the fast regime (R14/R15/R20); VGPR-92 builds collapse to
//   2.2ms (R16/R18/R19) regardless of weight-load source form.

#define T_STEPS 8
#define BATCH   16
#define CIN     64
#define COUT    64
#define IMH     64
#define IMW     64
#define HW      (IMH * IMW)
#define X_ELEMS (T_STEPS * BATCH * CIN * HW)   // 33,554,432
#define W_ELEMS (COUT * CIN * 9)               // 36,864

// [co][g] -> [g][co]: per (ci,k) step, a wave's 8 weights are one contiguous
// 32B block (2x float4, L2-hot).
__global__ void transpose_weights(const float* __restrict__ wf, float* __restrict__ wt) {
    int i = blockIdx.x * 256 + threadIdx.x;     // i = co*576 + g
    if (i < W_ELEMS) {
        int co = i / 576;
        int g  = i - co * 576;
        wt[g * 64 + co] = wf[i];
    }
}

__device__ __forceinline__ float stage_load(const float* xim, int h0, int w0,
                                            int q) {
    int ci  = q / 100;
    int rem = q - ci * 100;
    int hh  = rem / 10;
    int wl  = rem - hh * 10;
    int gh  = h0 - 1 + hh;
    int gw  = w0 - 1 + wl;
    float val = 0.0f;
    if ((unsigned)gh < IMH && (unsigned)gw < IMW)
        val = xim[ci * HW + gh * IMW + gw];
    return val;
}

__global__ __launch_bounds__(512, 8)
void snn_conv_lif_f0(const float* __restrict__ x, const float* __restrict__ wt,
                     float* __restrict__ out) {
    __shared__ float xt[CIN][10][12];   // padded stride 12: 30.7 KB

    const int tid  = threadIdx.x;        // 0..511
    const int lane = tid & 63;
    const int wid  = __builtin_amdgcn_readfirstlane(tid >> 6);   // 0..7

    const int b    = blockIdx.x >> 6;        // 0..15
    const int tile = blockIdx.x & 63;        // 64 tiles of 8x8
    const int h0   = (tile >> 3) << 3;
    const int w0   = (tile & 7) << 3;
    const int ph   = lane >> 3;
    const int pw   = lane & 7;
    const int cobase = wid << 3;             // 8 c_out per wave
    const int oh = h0 + ph, ow = w0 + pw;

    double v[8];                             // f64 LIF state
#pragma unroll
    for (int i = 0; i < 8; ++i) v[i] = 0.0;

    // prefetch t=0 staging values into registers (13 per thread, q<6400 guard)
    float r[13];
    {
        const float* xim = x + (size_t)b * CIN * HW;
#pragma unroll
        for (int j = 0; j < 13; ++j) {
            int q = tid + j * 512;
            r[j] = (q < 6400) ? stage_load(xim, h0, w0, q) : 0.0f;
        }
    }

    for (int t = 0; t < T_STEPS; ++t) {
        __syncthreads();                     // prior compute done reading xt
        // ---- write staged regs to (padded) LDS ----
#pragma unroll
        for (int j = 0; j < 13; ++j) {
            int q = tid + j * 512;           // 0..6399
            if (q < 6400) {
                int ci  = q / 100;
                int rem = q - ci * 100;
                int hh  = rem / 10;
                int wl  = rem - hh * 10;
                xt[ci][hh][wl] = r[j];
            }
        }
        __syncthreads();

        // ---- issue t+1 prefetch; HBM latency hides under the conv below ----
        if (t + 1 < T_STEPS) {
            const float* xim = x + (size_t)((t + 1) * BATCH + b) * CIN * HW;
#pragma unroll
            for (int j = 0; j < 13; ++j) {
                int q = tid + j * 512;
                r[j] = (q < 6400) ? stage_load(xim, h0, w0, q) : 0.0f;
            }
        }

        // ---- conv: per c_out, ONE sequential FMA chain over g = ci*9+k ----
        float z[8];
#pragma unroll
        for (int i = 0; i < 8; ++i) z[i] = 0.0f;

        for (int ci = 0; ci < CIN; ++ci) {
            float nb[9];
#pragma unroll
            for (int dy = 0; dy < 3; ++dy)
#pragma unroll
                for (int dx = 0; dx < 3; ++dx)
                    nb[dy * 3 + dx] = xt[ci][ph + dy][pw + dx];

#pragma unroll
            for (int k = 0; k < 9; ++k) {
                float xv = nb[k];
                const float4* w4 = (const float4*)(wt + (ci * 9 + k) * 64 + cobase);
                float4 wa = w4[0], wb = w4[1];
                z[0] = __builtin_fmaf(wa.x, xv, z[0]);
                z[1] = __builtin_fmaf(wa.y, xv, z[1]);
                z[2] = __builtin_fmaf(wa.z, xv, z[2]);
                z[3] = __builtin_fmaf(wa.w, xv, z[3]);
                z[4] = __builtin_fmaf(wb.x, xv, z[4]);
                z[5] = __builtin_fmaf(wb.y, xv, z[5]);
                z[6] = __builtin_fmaf(wb.z, xv, z[6]);
                z[7] = __builtin_fmaf(wb.w, xv, z[7]);
            }
        }

        // ---- f64 LIF scan ----
        size_t obase = ((size_t)(t * BATCH + b) * COUT + cobase) * HW
                     + (size_t)oh * IMW + ow;
#pragma unroll
        for (int i = 0; i < 8; ++i) {
            double d  = (double)z[i] - v[i];
            double nv = v[i] + d * 0.5;
            bool  sp  = (nv >= 1.0);
            out[obase + (size_t)i * HW] = sp ? 1.0f : 0.0f;
            v[i] = sp ? 0.0 : nv;
        }
    }
}

// Fallback without workspace: identical numerics (R14-style, 256 threads).
__global__ __launch_bounds__(256)
void snn_conv_lif_f0_direct(const float* __restrict__ x, const float* __restrict__ cw,
                            float* __restrict__ out) {
    __shared__ float xt[CIN][10][12];

    const int tid  = threadIdx.x;
    const int lane = tid & 63;
    const int wid  = __builtin_amdgcn_readfirstlane(tid >> 6);
    const int b    = blockIdx.x >> 6;
    const int tile = blockIdx.x & 63;
    const int h0   = (tile >> 3) << 3;
    const int w0   = (tile & 7) << 3;
    const int ph   = lane >> 3, pw = lane & 7;
    const int cobase = wid << 4;
    const int oh = h0 + ph, ow = w0 + pw;

    double v[16];
#pragma unroll
    for (int i = 0; i < 16; ++i) v[i] = 0.0;

    for (int t = 0; t < T_STEPS; ++t) {
        __syncthreads();
        const float* xim = x + (size_t)(t * BATCH + b) * CIN * HW;
#pragma unroll
        for (int j = 0; j < 25; ++j) {
            int q   = tid + j * 256;
            int ci  = q / 100;
            int rem = q - ci * 100;
            int hh  = rem / 10;
            int wl  = rem - hh * 10;
            xt[ci][hh][wl] = stage_load(xim, h0, w0, q);
        }
        __syncthreads();

        float z[16];
#pragma unroll
        for (int i = 0; i < 16; ++i) z[i] = 0.0f;

        for (int ci = 0; ci < CIN; ++ci) {
            float nb[9];
#pragma unroll
            for (int dy = 0; dy < 3; ++dy)
#pragma unroll
                for (int dx = 0; dx < 3; ++dx)
                    nb[dy * 3 + dx] = xt[ci][ph + dy][pw + dx];
            const float* wp = cw + ci * 9;
#pragma unroll
            for (int k = 0; k < 9; ++k) {
                float xv = nb[k];
#pragma unroll
                for (int i = 0; i < 16; ++i)
                    z[i] = __builtin_fmaf(wp[(cobase + i) * (CIN * 9) + k], xv, z[i]);
            }
        }

        size_t obase = ((size_t)(t * BATCH + b) * COUT + cobase) * HW
                     + (size_t)oh * IMW + ow;
#pragma unroll
        for (int i = 0; i < 16; ++i) {
            double d  = (double)z[i] - v[i];
            double nv = v[i] + d * 0.5;
            bool  sp  = (nv >= 1.0);
            out[obase + (size_t)i * HW] = sp ? 1.0f : 0.0f;
            v[i] = sp ? 0.0 : nv;
        }
    }
}

extern "C" void kernel_launch(void* const* d_in, const int* in_sizes, int n_in,
                              void* d_out, int out_size, void* d_ws, size_t ws_size,
                              hipStream_t stream) {
    // Resolve inputs by size: x = 33.5M elems, conv_w = 36864.
    const float* x  = (const float*)d_in[0];
    const float* wf = (const float*)d_in[1];
    if (n_in >= 2) {
        if (in_sizes[0] == W_ELEMS || in_sizes[1] == X_ELEMS) {
            x  = (const float*)d_in[1];
            wf = (const float*)d_in[0];
        }
    }
    float* out = (float*)d_out;
    (void)out_size;

    if (ws_size >= (size_t)W_ELEMS * sizeof(float)) {
        float* wt = (float*)d_ws;
        hipLaunchKernelGGL(transpose_weights, dim3((W_ELEMS + 255) / 256), dim3(256), 0, stream, wf, wt);
        hipLaunchKernelGGL(snn_conv_lif_f0, dim3(BATCH * 64), dim3(512), 0, stream, x, wt, out);
    } else {
        hipLaunchKernelGGL(snn_conv_lif_f0_direct, dim3(BATCH * 64), dim3(256), 0, stream, x, wf, out);
    }
}